// Round 2
// baseline (1098.620 us; speedup 1.0000x reference)
//
#include <hip/hip_runtime.h>

// FusedLoRA: x[4,4096,4096] f32; 3x (A[4096,8], B[8,4096]) f32
// out[16384][12288] = concat_l( (x @ A_l) @ B_l ), scale = 1.0
//
// R6: FUSED single kernel. Dependency is row-local (out row r needs only
// xa[r]), so each block: (stage A) computes xa for its 8 rows exactly like
// the old phase-1, writes them to LDS; (stage B) expands those 8 rows to
// out. Removes the kernel boundary so phase-1 compute/LDS time overlaps
// phase-2 HBM writes across blocks, removes one launch + xa round-trip.
// Cost: B re-read per block = 2048 x 384 KB = 786 MB from L2 (~23 us agg).
//
// History: R3: ROWS_PER_WAVE=4 + prefetch spilled; 2 rows/wave fits.
// R4: NT store needs ext_vector_type. R5: NT->cached + LDS xa = null
// (phase 2 was already at its ~128 us write floor, not store-path-bound).

#define DIM       4096
#define M_ROWS    16384
#define RANK      8
#define NC        24
#define OUT_COLS  12288

typedef float floatx4 __attribute__((ext_vector_type(4)));

#define KC             512       // At = 24*512*4 = 48 KB LDS -> 3 blocks/CU
#define ROWS_PER_WAVE  2
#define ROWS_PER_BLOCK 8         // 4 waves * 2 rows

__launch_bounds__(256, 3)
__global__ void lora_fused_kernel(const float* __restrict__ x,
                                  const float* __restrict__ A0,
                                  const float* __restrict__ A1,
                                  const float* __restrict__ A2,
                                  const float* __restrict__ B0,
                                  const float* __restrict__ B1,
                                  const float* __restrict__ B2,
                                  float* __restrict__ out) {
  // Transposed A chunk: compute read At[c][4*lane] is 16B-contiguous across
  // lanes -> conflict-free ds_read_b128.
  __shared__ float At[NC][KC];
  __shared__ float sxa[ROWS_PER_BLOCK][NC];     // 768 B: this block's xa

  const int tid  = threadIdx.x;
  const int lane = tid & 63;
  const int wave = tid >> 6;
  const int brow = blockIdx.x * ROWS_PER_BLOCK;
  const int row0 = brow + wave * ROWS_PER_WAVE;

  // ---------------- stage A: xa[8][24] = x_rows @ [A0|A1|A2] ------------
  float acc[ROWS_PER_WAVE][NC];                  // 48 VGPR
#pragma unroll
  for (int r = 0; r < ROWS_PER_WAVE; ++r)
#pragma unroll
    for (int c = 0; c < NC; ++c) acc[r][c] = 0.f;

  for (int kb = 0; kb < DIM; kb += KC) {
    // prefetch this chunk's x before the staging barrier (16 VGPR)
    float4 xv[2][ROWS_PER_WAVE];
#pragma unroll
    for (int step = 0; step < 2; ++step)
#pragma unroll
      for (int r = 0; r < ROWS_PER_WAVE; ++r)
        xv[step][r] = *(const float4*)(x + (size_t)(row0 + r) * DIM + kb +
                                       step * 256 + 4 * lane);

    // stage A chunk transposed into LDS:
    // per lora KC*8 floats = 1024 float4; 3 loras = 3072 float4 / 256 thr = 12
#pragma unroll
    for (int j = 0; j < 12; ++j) {
      const int l   = j >> 2;                    // compile-time after unroll
      const int idx = tid + (j & 3) * 256;       // float4 index within lora chunk
      const int dof = idx >> 1;                  // k offset in chunk
      const int rq  = (idx & 1) * 4;             // rank quad: 0 or 4
      const float* Ap = (l == 0) ? A0 : (l == 1) ? A1 : A2;
      const float4 v = *(const float4*)(Ap + (size_t)(kb + dof) * RANK + rq);
      At[l * RANK + rq + 0][dof] = v.x;
      At[l * RANK + rq + 1][dof] = v.y;
      At[l * RANK + rq + 2][dof] = v.z;
      At[l * RANK + rq + 3][dof] = v.w;
    }
    __syncthreads();

#pragma unroll
    for (int step = 0; step < 2; ++step) {
      const int kl = step * 256 + 4 * lane;
#pragma unroll
      for (int c = 0; c < NC; ++c) {
        const float4 av = *(const float4*)(&At[c][kl]);
#pragma unroll
        for (int r = 0; r < ROWS_PER_WAVE; ++r) {
          acc[r][c] = fmaf(xv[step][r].x, av.x, acc[r][c]);
          acc[r][c] = fmaf(xv[step][r].y, av.y, acc[r][c]);
          acc[r][c] = fmaf(xv[step][r].z, av.z, acc[r][c]);
          acc[r][c] = fmaf(xv[step][r].w, av.w, acc[r][c]);
        }
      }
    }
    __syncthreads();
  }

  // 64-lane butterfly reduction per (row, col)
#pragma unroll
  for (int r = 0; r < ROWS_PER_WAVE; ++r)
#pragma unroll
    for (int c = 0; c < NC; ++c) {
      float v = acc[r][c];
#pragma unroll
      for (int off = 32; off > 0; off >>= 1) v += __shfl_xor(v, off, 64);
      acc[r][c] = v;
    }

  float outv[ROWS_PER_WAVE];
#pragma unroll
  for (int c = 0; c < NC; ++c)
#pragma unroll
    for (int r = 0; r < ROWS_PER_WAVE; ++r)
      if (lane == c) outv[r] = acc[r][c];

  if (lane < NC) {
#pragma unroll
    for (int r = 0; r < ROWS_PER_WAVE; ++r)
      sxa[wave * ROWS_PER_WAVE + r][lane] = outv[r];
  }
  __syncthreads();

  // ---------------- stage B: out[8][12288] = sxa @ blockdiag(B) ---------
  // 12 column groups of 1024; per group: B slice -> 8 float4 regs (L2-hit),
  // then 8 rows x (uniform LDS read + 32 fma + 1 KB/wave coalesced store).
  const int tid4 = tid * 4;
#pragma unroll 1
  for (int g = 0; g < 12; ++g) {
    const int l = g >> 2;
    const int o = (g & 3) * 1024 + tid4;
    const float* B = (l == 0) ? B0 : (l == 1) ? B1 : B2;

    float4 b[RANK];                             // 32 VGPR
#pragma unroll
    for (int r = 0; r < RANK; ++r)
      b[r] = *(const float4*)(B + (size_t)r * DIM + o);

    const size_t ocol = (size_t)l * DIM + o;
#pragma unroll
    for (int i = 0; i < ROWS_PER_BLOCK; ++i) {
      const float4 s0 = *(const float4*)(&sxa[i][l * RANK]);
      const float4 s1 = *(const float4*)(&sxa[i][l * RANK + 4]);
      const float s[8] = {s0.x, s0.y, s0.z, s0.w, s1.x, s1.y, s1.z, s1.w};

      floatx4 a4 = {0.f, 0.f, 0.f, 0.f};
#pragma unroll
      for (int r = 0; r < RANK; ++r) {
        a4.x = fmaf(s[r], b[r].x, a4.x);
        a4.y = fmaf(s[r], b[r].y, a4.y);
        a4.z = fmaf(s[r], b[r].z, a4.z);
        a4.w = fmaf(s[r], b[r].w, a4.w);
      }
      *(floatx4*)(out + (size_t)(brow + i) * OUT_COLS + ocol) = a4;
    }
  }
}

extern "C" void kernel_launch(void* const* d_in, const int* in_sizes, int n_in,
                              void* d_out, int out_size, void* d_ws, size_t ws_size,
                              hipStream_t stream) {
  const float* x  = (const float*)d_in[0];
  const float* A0 = (const float*)d_in[1];
  const float* B0 = (const float*)d_in[2];
  const float* A1 = (const float*)d_in[3];
  const float* B1 = (const float*)d_in[4];
  const float* A2 = (const float*)d_in[5];
  const float* B2 = (const float*)d_in[6];
  float* out = (float*)d_out;

  lora_fused_kernel<<<dim3(M_ROWS / ROWS_PER_BLOCK), dim3(256), 0, stream>>>(
      x, A0, A1, A2, B0, B1, B2, out);
}